// Round 1
// baseline (5520.774 us; speedup 1.0000x reference)
//
#include <hip/hip_runtime.h>

#define NB 2
#define NC 64
#define ND 12
#define NH 256
#define NW 64
#define CSTRIDE (ND*NH*NW)   // 196608, channel stride in rep/out

__device__ __forceinline__ unsigned int bf_round(float f){
    unsigned int u = __float_as_uint(f);
    unsigned int r = (u + 0x7fffu + ((u >> 16) & 1u)) >> 16;   // RNE bf16
    return r;
}
__device__ __forceinline__ unsigned int pack_bf2(float f0, float f1){
    return bf_round(f0) | (bf_round(f1) << 16);
}
__device__ __forceinline__ float bflo(unsigned int u){ return __uint_as_float(u << 16); }
__device__ __forceinline__ float bfhi(unsigned int u){ return __uint_as_float(u & 0xffff0000u); }

__global__ __launch_bounds__(256) void sa_fused(
    const float* __restrict__ rep,
    const float* __restrict__ Wq, const float* __restrict__ bq,
    const float* __restrict__ Wk, const float* __restrict__ bk,
    const float* __restrict__ Wv, const float* __restrict__ bv,
    const float* __restrict__ Wf, const float* __restrict__ bfc,
    float* __restrict__ out)
{
    // K/V rows in packed bf16 pairs: [h][32 u32] (row = 128B, 16B aligned)
    __shared__ __align__(16) unsigned int k_u[NH*32];
    __shared__ __align__(16) unsigned int v_u[NH*32];

    const int t  = threadIdx.x;          // h row this thread owns
    const int blk = blockIdx.x;          // (b*ND + d)*NW + w
    const int w  = blk & 63;
    const int bd = blk >> 6;
    const int d  = bd % ND;
    const int b  = bd / ND;

    const long base_x = (long)b*(NC*CSTRIDE) + (long)d*(NH*NW) + (long)t*NW + w;

    // ---- load x column (c-strided; uncoalesced but L2/L3-absorbed) ----
    float xc[NC];
#pragma unroll
    for (int c = 0; c < NC; ++c) xc[c] = rep[base_x + (long)c*CSTRIDE];

    // ---- k,v rows -> LDS bf16 (o in pairs so we write packed u32) ----
    for (int o2 = 0; o2 < 32; ++o2){
        const int o0 = 2*o2, o1 = 2*o2 + 1;
        float ka0 = bk[o0], ka1 = bk[o1];
        float va0 = bv[o0], va1 = bv[o1];
#pragma unroll
        for (int c = 0; c < NC; ++c){
            const float x = xc[c];
            ka0 += Wk[o0*NC + c] * x;
            ka1 += Wk[o1*NC + c] * x;
            va0 += Wv[o0*NC + c] * x;
            va1 += Wv[o1*NC + c] * x;
        }
        ka0 = fmaxf(ka0, 0.f); ka1 = fmaxf(ka1, 0.f);
        va0 = fmaxf(va0, 0.f); va1 = fmaxf(va1, 0.f);
        k_u[t*32 + o2] = pack_bf2(ka0, ka1);
        v_u[t*32 + o2] = pack_bf2(va0, va1);
    }

    // ---- q row in f32 registers (o unrolled so q[] is statically indexed) ----
    float q[NC];
#pragma unroll
    for (int o = 0; o < NC; ++o) q[o] = bq[o];
    for (int c = 0; c < NC; ++c){
        const float x = rep[base_x + (long)c*CSTRIDE];   // reload, L1/L2-hot
#pragma unroll
        for (int o = 0; o < NC; ++o) q[o] += Wq[o*NC + c] * x;
    }
#pragma unroll
    for (int o = 0; o < NC; ++o) q[o] = fmaxf(q[o], 0.f) * 0.125f;  // fold 1/sqrt(C)

    __syncthreads();

    // ---- online softmax attention over g = 0..255 in chunks of 16 ----
    float m = -1e30f, l = 0.f;
    float acc[NC];
#pragma unroll
    for (int c = 0; c < NC; ++c) acc[c] = 0.f;

    for (int g0 = 0; g0 < NH; g0 += 16){
        float s[16];
#pragma unroll
        for (int j = 0; j < 16; ++j){
            const uint4* kr = (const uint4*)&k_u[(g0 + j)*32];
            float a0 = 0.f, a1 = 0.f, a2 = 0.f, a3 = 0.f;
#pragma unroll
            for (int c4 = 0; c4 < 8; ++c4){
                const uint4 k4 = kr[c4];
                a0 += q[c4*8+0]*bflo(k4.x) + q[c4*8+1]*bfhi(k4.x);
                a1 += q[c4*8+2]*bflo(k4.y) + q[c4*8+3]*bfhi(k4.y);
                a2 += q[c4*8+4]*bflo(k4.z) + q[c4*8+5]*bfhi(k4.z);
                a3 += q[c4*8+6]*bflo(k4.w) + q[c4*8+7]*bfhi(k4.w);
            }
            s[j] = (a0 + a1) + (a2 + a3);
        }
        float cm = s[0];
#pragma unroll
        for (int j = 1; j < 16; ++j) cm = fmaxf(cm, s[j]);
        const float mn = fmaxf(m, cm);
        const float corr = __expf(m - mn);
        l *= corr;
#pragma unroll
        for (int c = 0; c < NC; ++c) acc[c] *= corr;
#pragma unroll
        for (int j = 0; j < 16; ++j){ const float e = __expf(s[j] - mn); l += e; s[j] = e; }
#pragma unroll
        for (int j = 0; j < 16; ++j){
            const uint4* vr = (const uint4*)&v_u[(g0 + j)*32];
            const float p = s[j];
#pragma unroll
            for (int c4 = 0; c4 < 8; ++c4){
                const uint4 v4 = vr[c4];
                acc[c4*8+0] += p*bflo(v4.x); acc[c4*8+1] += p*bfhi(v4.x);
                acc[c4*8+2] += p*bflo(v4.y); acc[c4*8+3] += p*bfhi(v4.y);
                acc[c4*8+4] += p*bflo(v4.z); acc[c4*8+5] += p*bfhi(v4.z);
                acc[c4*8+6] += p*bflo(v4.w); acc[c4*8+7] += p*bfhi(v4.w);
            }
        }
        m = mn;
    }
    const float inv_l = 1.f / l;

    // ---- final FC + ReLU, write out (B,C,D,H,W) ----
    for (int o = 0; o < NC; ++o){
        float a = 0.f;
#pragma unroll
        for (int c = 0; c < NC; ++c) a += Wf[o*NC + c] * acc[c];
        const float r = fmaxf(a*inv_l + bfc[o], 0.f);
        out[base_x + (long)o*CSTRIDE] = r;
    }
}

extern "C" void kernel_launch(void* const* d_in, const int* in_sizes, int n_in,
                              void* d_out, int out_size, void* d_ws, size_t ws_size,
                              hipStream_t stream) {
    const float* rep = (const float*)d_in[0];
    const float* Wq  = (const float*)d_in[1];
    const float* bq  = (const float*)d_in[2];
    const float* Wk  = (const float*)d_in[3];
    const float* bk  = (const float*)d_in[4];
    const float* Wv  = (const float*)d_in[5];
    const float* bv  = (const float*)d_in[6];
    const float* Wf  = (const float*)d_in[7];
    const float* bfc = (const float*)d_in[8];
    float* out = (float*)d_out;

    dim3 grid(NB*ND*NW);   // 1536 blocks, one per (b,d,w)
    dim3 block(256);       // thread t owns attention row h=t
    sa_fused<<<grid, block, 0, stream>>>(rep, Wq, bq, Wk, bk, Wv, bv, Wf, bfc, out);
}

// Round 2
// 524.579 us; speedup vs baseline: 10.5242x; 10.5242x over previous
//
#include <hip/hip_runtime.h>

typedef float f32x4 __attribute__((ext_vector_type(4)));
typedef short bf16x8 __attribute__((ext_vector_type(8)));
typedef unsigned short ushort_t;

#define NB 2
#define NC 64
#define ND 12
#define NH 256
#define NW 64
#define CSTRIDE (ND*NH*NW)   // 196608

__device__ __forceinline__ ushort_t bf_round(float f){
    unsigned int u = __float_as_uint(f);
    return (ushort_t)((u + 0x7fffu + ((u >> 16) & 1u)) >> 16);   // RNE
}
__device__ __forceinline__ float bf_to_f(ushort_t s){ return __uint_as_float(((unsigned int)s) << 16); }

union U4S8 { uint4 u; bf16x8 s; };

// swizzled byte offsets: [R][64]-bf16 row-major, 8-elem (16B) chunks, chunk ^= row&7
__device__ __forceinline__ int row64_off(int r, int o){
    return r*128 + ((((o>>3) ^ (r&7)))<<4) + (o&7)*2;
}
__device__ __forceinline__ int row64_chunk(int r, int kchunk){
    return r*128 + (((kchunk ^ (r&7)))<<4);
}
// Vt: [64 c][256 g] bf16, rowbytes 512, 32 chunks, chunk ^= c&7 (low 3 bits)
__device__ __forceinline__ int vt_off(int c, int g){
    return c*512 + ((((g>>3) ^ (c&7)))<<4) + (g&7)*2;
}
__device__ __forceinline__ int vt_chunk(int c, int gchunk){
    return c*512 + (((gchunk ^ (c&7)))<<4);
}

__global__ __launch_bounds__(256, 2) void sa_mfma(
    const float* __restrict__ rep,
    const float* __restrict__ Wq, const float* __restrict__ bq,
    const float* __restrict__ Wk, const float* __restrict__ bk,
    const float* __restrict__ Wv, const float* __restrict__ bv,
    const float* __restrict__ Wf, const float* __restrict__ bfc,
    float* __restrict__ out)
{
    __shared__ __align__(16) unsigned char smem[65536];
    unsigned char* BUFA = smem;          // Q-bounce -> K_lds -> O_hi
    unsigned char* BUFB = smem + 32768;  // X_lds    -> Vt_lds -> O_lo

    const int t = threadIdx.x, lane = t & 63, wid = t >> 6;
    const int G = lane >> 4, hl = lane & 15;
    const int blk = blockIdx.x;
    const int w = blk & 63, bd = blk >> 6, d = bd % ND, b = bd / ND;
    const long base_bd = (long)b*(NC*CSTRIDE) + (long)d*(NH*NW) + w;

    // ================= stage X -> LDS bf16 (swizzled), thread t owns row h=t ==========
    {
        const int h = t;
        const long rbase = base_bd + (long)h*NW;
#pragma unroll
        for (int c8 = 0; c8 < 8; ++c8){
            U4S8 u;
            ushort_t* s = (ushort_t*)&u;
#pragma unroll
            for (int j = 0; j < 8; ++j)
                s[j] = bf_round(rep[rbase + (long)(c8*8 + j)*CSTRIDE]);
            *(uint4*)(BUFB + row64_chunk(h, c8)) = u.u;
        }
    }
    // wave-local: each wave reads only its own 64 rows below (no barrier needed)

    // X A-frags, shared by all three projections: row h = 64*wid+16*ht+hl, k c = 32m+8G+j
    U4S8 xafr[4][2];
#pragma unroll
    for (int ht = 0; ht < 4; ++ht)
#pragma unroll
        for (int m = 0; m < 2; ++m)
            xafr[ht][m].u = *(const uint4*)(BUFB + row64_chunk(64*wid + 16*ht + hl, 4*m + G));

    // weight B/A-frag builder: lane needs W[hl+16*ot][32m+8G .. +8] as bf16x8
    auto wfrag = [&](const float* W, int ot, int m)->U4S8 {
        const float* p = W + (hl + 16*ot)*NC + 32*m + 8*G;
        float4 f0 = *(const float4*)p;
        float4 f1 = *(const float4*)(p + 4);
        U4S8 u; ushort_t* s = (ushort_t*)&u;
        s[0]=bf_round(f0.x); s[1]=bf_round(f0.y); s[2]=bf_round(f0.z); s[3]=bf_round(f0.w);
        s[4]=bf_round(f1.x); s[5]=bf_round(f1.y); s[6]=bf_round(f1.z); s[7]=bf_round(f1.w);
        return u;
    };

    // projection: D[h,o] = relu(X·W^T + b) * scale ; D rows h (tile ht), cols o (tile ot)
    auto do_proj = [&](const float* W, const float* bias, float scale, f32x4 (&acc)[4][4]){
        U4S8 bw[4][2];
#pragma unroll
        for (int ot = 0; ot < 4; ++ot){ bw[ot][0] = wfrag(W, ot, 0); bw[ot][1] = wfrag(W, ot, 1); }
        float bb[4];
#pragma unroll
        for (int ot = 0; ot < 4; ++ot) bb[ot] = bias[hl + 16*ot];
#pragma unroll
        for (int ht = 0; ht < 4; ++ht)
#pragma unroll
            for (int ot = 0; ot < 4; ++ot){
                f32x4 a = {0.f, 0.f, 0.f, 0.f};
                a = __builtin_amdgcn_mfma_f32_16x16x32_bf16(xafr[ht][0].s, bw[ot][0].s, a, 0, 0, 0);
                a = __builtin_amdgcn_mfma_f32_16x16x32_bf16(xafr[ht][1].s, bw[ot][1].s, a, 0, 0, 0);
#pragma unroll
                for (int r = 0; r < 4; ++r) a[r] = fmaxf(a[r] + bb[ot], 0.f) * scale;
                acc[ht][ot] = a;
            }
    };

    // ---- Q projection -> bounce through BUFA (own quarter) -> B-frags in regs ----
    {
        f32x4 qa[4][4];
        do_proj(Wq, bq, 0.125f, qa);   // fold 1/sqrt(C)
#pragma unroll
        for (int ht = 0; ht < 4; ++ht)
#pragma unroll
            for (int ot = 0; ot < 4; ++ot)
#pragma unroll
                for (int r = 0; r < 4; ++r){
                    int h = 64*wid + 16*ht + 4*G + r;
                    int o = hl + 16*ot;
                    *(ushort_t*)(BUFA + row64_off(h, o)) = bf_round(qa[ht][ot][r]);
                }
    }
    U4S8 qfr[4][2];
#pragma unroll
    for (int ht = 0; ht < 4; ++ht)
#pragma unroll
        for (int m = 0; m < 2; ++m)
            qfr[ht][m].u = *(const uint4*)(BUFA + row64_chunk(64*wid + 16*ht + hl, 4*m + G));

    // ---- K projection -> write K_lds (BUFA, own quarter; Q-bounce already consumed) ----
    {
        f32x4 ka[4][4];
        do_proj(Wk, bk, 1.0f, ka);
#pragma unroll
        for (int gt = 0; gt < 4; ++gt)
#pragma unroll
            for (int ot = 0; ot < 4; ++ot)
#pragma unroll
                for (int r = 0; r < 4; ++r){
                    int g = 64*wid + 16*gt + 4*G + r;
                    int o = hl + 16*ot;
                    *(ushort_t*)(BUFA + row64_off(g, o)) = bf_round(ka[gt][ot][r]);
                }
    }

    // ---- V projection (keep in regs until X fully dead across ALL waves) ----
    f32x4 va[4][4];
    do_proj(Wv, bv, 1.0f, va);

    __syncthreads();   // all waves done reading X (BUFB) -> safe to overwrite with Vt

#pragma unroll
    for (int gt = 0; gt < 4; ++gt)
#pragma unroll
        for (int ot = 0; ot < 4; ++ot)
#pragma unroll
            for (int r = 0; r < 4; ++r){
                int g = 64*wid + 16*gt + 4*G + r;
                int c = hl + 16*ot;
                *(ushort_t*)(BUFB + vt_off(c, g)) = bf_round(va[gt][ot][r]);
            }

    __syncthreads();   // K_lds + Vt_lds complete

    // ================= flash attention over g-tiles of 64 =================
    f32x4 oacc[4][4];   // [ct][ht]: O'[c,h]
#pragma unroll
    for (int ct = 0; ct < 4; ++ct)
#pragma unroll
        for (int ht = 0; ht < 4; ++ht) oacc[ct][ht] = (f32x4){0.f,0.f,0.f,0.f};
    float m_run[4], l_run[4];
#pragma unroll
    for (int ht = 0; ht < 4; ++ht){ m_run[ht] = -1e30f; l_run[ht] = 0.f; }

    const int srcq0 = (16*((2*G    ) & 3) + hl)*4;   // bpermute byte addrs
    const int srcq1 = (16*((2*G + 1) & 3) + hl)*4;

    for (int gb = 0; gb < NH; gb += 64){
        // S'[g,h] = K·Q^T : A = K rows g, B = Q^T cols h, k = o
        U4S8 kfr[4][2];
#pragma unroll
        for (int gt = 0; gt < 4; ++gt)
#pragma unroll
            for (int m = 0; m < 2; ++m)
                kfr[gt][m].u = *(const uint4*)(BUFA + row64_chunk(gb + 16*gt + hl, 4*m + G));

        f32x4 sacc[4][4];   // [gt][ht]
#pragma unroll
        for (int gt = 0; gt < 4; ++gt)
#pragma unroll
            for (int ht = 0; ht < 4; ++ht){
                f32x4 a = {0.f,0.f,0.f,0.f};
                a = __builtin_amdgcn_mfma_f32_16x16x32_bf16(kfr[gt][0].s, qfr[ht][0].s, a, 0,0,0);
                a = __builtin_amdgcn_mfma_f32_16x16x32_bf16(kfr[gt][1].s, qfr[ht][1].s, a, 0,0,0);
                sacc[gt][ht] = a;
            }

        // online softmax per h-col (lane holds 16 g-values per ht; 4 G-groups complete it)
        unsigned int pk[4][4][2];   // [ht][gt][pair] packed bf16 P
#pragma unroll
        for (int ht = 0; ht < 4; ++ht){
            float cm = -1e30f;
#pragma unroll
            for (int gt = 0; gt < 4; ++gt)
#pragma unroll
                for (int r = 0; r < 4; ++r) cm = fmaxf(cm, sacc[gt][ht][r]);
            cm = fmaxf(cm, __shfl_xor(cm, 16));
            cm = fmaxf(cm, __shfl_xor(cm, 32));
            const float mn  = fmaxf(m_run[ht], cm);
            const float corr = __expf(m_run[ht] - mn);
            m_run[ht] = mn;
            float ls = 0.f;
#pragma unroll
            for (int gt = 0; gt < 4; ++gt){
                f32x4 s = sacc[gt][ht];
                float e0 = __expf(s[0]-mn), e1 = __expf(s[1]-mn);
                float e2 = __expf(s[2]-mn), e3 = __expf(s[3]-mn);
                ls += (e0+e1)+(e2+e3);
                pk[ht][gt][0] = (unsigned int)bf_round(e0) | ((unsigned int)bf_round(e1) << 16);
                pk[ht][gt][1] = (unsigned int)bf_round(e2) | ((unsigned int)bf_round(e3) << 16);
            }
            ls += __shfl_xor(ls, 16);
            ls += __shfl_xor(ls, 32);
            l_run[ht] = l_run[ht]*corr + ls;
#pragma unroll
            for (int ct = 0; ct < 4; ++ct)
#pragma unroll
                for (int r = 0; r < 4; ++r) oacc[ct][ht][r] *= corr;
        }

        // V^T A-frags and P B-frags (in-register transpose via ds_bpermute), then PV
        U4S8 vfr[4][2];
#pragma unroll
        for (int ct = 0; ct < 4; ++ct)
#pragma unroll
            for (int m = 0; m < 2; ++m)
                vfr[ct][m].u = *(const uint4*)(BUFB + vt_chunk(16*ct + hl, (gb>>3) + 4*m + G));

#pragma unroll
        for (int m = 0; m < 2; ++m){
            U4S8 bfr[4];
#pragma unroll
            for (int ht = 0; ht < 4; ++ht){
                unsigned int wv[4];
#pragma unroll
                for (int jj = 0; jj < 4; ++jj){
                    const int src = (jj >> 1) ? srcq1 : srcq0;
                    const int p2  = jj & 1;
                    int rA = __builtin_amdgcn_ds_bpermute(src, (int)pk[ht][2*m  ][p2]);
                    int rB = __builtin_amdgcn_ds_bpermute(src, (int)pk[ht][2*m+1][p2]);
                    wv[jj] = (lane < 32) ? (unsigned int)rA : (unsigned int)rB;
                }
                bfr[ht].u = make_uint4(wv[0], wv[1], wv[2], wv[3]);
            }
#pragma unroll
            for (int ct = 0; ct < 4; ++ct)
#pragma unroll
                for (int ht = 0; ht < 4; ++ht)
                    oacc[ct][ht] = __builtin_amdgcn_mfma_f32_16x16x32_bf16(vfr[ct][m].s, bfr[ht].s, oacc[ct][ht], 0,0,0);
        }
    }

    // ================= epilogue: 1/l, O -> LDS (hi+lo bf16 split), FC, store ============
    float invl[4];
#pragma unroll
    for (int ht = 0; ht < 4; ++ht) invl[ht] = 1.f / l_run[ht];

    __syncthreads();   // all waves done reading K_lds / Vt_lds

#pragma unroll
    for (int ct = 0; ct < 4; ++ct)
#pragma unroll
        for (int ht = 0; ht < 4; ++ht)
#pragma unroll
            for (int r = 0; r < 4; ++r){
                float v = oacc[ct][ht][r] * invl[ht];
                ushort_t hi = bf_round(v);
                ushort_t lo = bf_round(v - bf_to_f(hi));
                int hrow = 64*wid + 16*ht + hl;
                int c = 16*ct + 4*G + r;
                *(ushort_t*)(BUFA + row64_off(hrow, c)) = hi;
                *(ushort_t*)(BUFB + row64_off(hrow, c)) = lo;
            }
    // wave-local below (own h-strip): no barrier needed

    U4S8 bh[4][2], bl[4][2];
#pragma unroll
    for (int ht = 0; ht < 4; ++ht)
#pragma unroll
        for (int m = 0; m < 2; ++m){
            bh[ht][m].u = *(const uint4*)(BUFA + row64_chunk(64*wid + 16*ht + hl, 4*m + G));
            bl[ht][m].u = *(const uint4*)(BUFB + row64_chunk(64*wid + 16*ht + hl, 4*m + G));
        }

    f32x4 yacc[4][4];
#pragma unroll
    for (int ot = 0; ot < 4; ++ot)
#pragma unroll
        for (int ht = 0; ht < 4; ++ht) yacc[ot][ht] = (f32x4){0.f,0.f,0.f,0.f};

#pragma unroll
    for (int ot = 0; ot < 4; ++ot)
#pragma unroll
        for (int m = 0; m < 2; ++m){
            U4S8 wf = wfrag(Wf, ot, m);
#pragma unroll
            for (int ht = 0; ht < 4; ++ht){
                yacc[ot][ht] = __builtin_amdgcn_mfma_f32_16x16x32_bf16(wf.s, bh[ht][m].s, yacc[ot][ht], 0,0,0);
                yacc[ot][ht] = __builtin_amdgcn_mfma_f32_16x16x32_bf16(wf.s, bl[ht][m].s, yacc[ot][ht], 0,0,0);
            }
        }

    float bfv[4][4];
#pragma unroll
    for (int ot = 0; ot < 4; ++ot)
#pragma unroll
        for (int r = 0; r < 4; ++r) bfv[ot][r] = bfc[16*ot + 4*G + r];

#pragma unroll
    for (int ot = 0; ot < 4; ++ot)
#pragma unroll
        for (int ht = 0; ht < 4; ++ht)
#pragma unroll
            for (int r = 0; r < 4; ++r){
                int o = 16*ot + 4*G + r;
                int h = 64*wid + 16*ht + hl;
                float y = fmaxf(yacc[ot][ht][r] + bfv[ot][r], 0.f);
                out[base_bd + (long)o*CSTRIDE + (long)h*NW] = y;
            }
}

extern "C" void kernel_launch(void* const* d_in, const int* in_sizes, int n_in,
                              void* d_out, int out_size, void* d_ws, size_t ws_size,
                              hipStream_t stream) {
    (void)in_sizes; (void)n_in; (void)d_ws; (void)ws_size; (void)out_size;
    const float* rep = (const float*)d_in[0];
    const float* Wq  = (const float*)d_in[1];
    const float* bq  = (const float*)d_in[2];
    const float* Wk  = (const float*)d_in[3];
    const float* bk  = (const float*)d_in[4];
    const float* Wv  = (const float*)d_in[5];
    const float* bv  = (const float*)d_in[6];
    const float* Wf  = (const float*)d_in[7];
    const float* bfc = (const float*)d_in[8];
    float* out = (float*)d_out;

    dim3 grid(NB*ND*NW);   // 1536 blocks: one per (b,d,w)
    dim3 block(256);       // 4 waves; wave wid owns h-strip [64*wid, 64*wid+64)
    sa_mfma<<<grid, block, 0, stream>>>(rep, Wq, bq, Wk, bk, Wv, bv, Wf, bfc, out);
}

// Round 3
// 243.489 us; speedup vs baseline: 22.6736x; 2.1544x over previous
//
#include <hip/hip_runtime.h>

typedef float f32x4 __attribute__((ext_vector_type(4)));
typedef short bf16x8 __attribute__((ext_vector_type(8)));
typedef unsigned short ushort_t;

#define NB 2
#define NC 64
#define ND 12
#define NH 256
#define NW 64
#define CSTRIDE (ND*NH*NW)   // 196608

__device__ __forceinline__ ushort_t bf_round(float f){
    unsigned int u = __float_as_uint(f);
    return (ushort_t)((u + 0x7fffu + ((u >> 16) & 1u)) >> 16);   // RNE
}
__device__ __forceinline__ float bf_to_f(ushort_t s){ return __uint_as_float(((unsigned int)s) << 16); }

union U4S8 { uint4 u; bf16x8 s; };

// swizzled byte offsets: [R][64]-bf16 row-major, 8-elem (16B) chunks, chunk ^= row&7
__device__ __forceinline__ int row64_off(int r, int o){
    return r*128 + ((((o>>3) ^ (r&7)))<<4) + (o&7)*2;
}
__device__ __forceinline__ int row64_chunk(int r, int kchunk){
    return r*128 + (((kchunk ^ (r&7)))<<4);
}
// Vt: [64 c][256 g] bf16, rowbytes 512, 32 chunks, chunk ^= c&7 (low 3 bits)
__device__ __forceinline__ int vt_off(int c, int g){
    return c*512 + ((((g>>3) ^ (c&7)))<<4) + (g&7)*2;
}
__device__ __forceinline__ int vt_chunk(int c, int gchunk){
    return c*512 + (((gchunk ^ (c&7)))<<4);
}

__global__ __launch_bounds__(256, 2) void sa_mfma(
    const float* __restrict__ rep,
    const float* __restrict__ Wq, const float* __restrict__ bq,
    const float* __restrict__ Wk, const float* __restrict__ bk,
    const float* __restrict__ Wv, const float* __restrict__ bv,
    const float* __restrict__ Wf, const float* __restrict__ bfc,
    float* __restrict__ out)
{
    __shared__ __align__(16) unsigned char smem[65536];
    unsigned char* BUFA = smem;          // Q-bounce -> K_lds -> O_hi
    unsigned char* BUFB = smem + 32768;  // X_lds    -> Vt_lds -> O_lo

    const int t = threadIdx.x, lane = t & 63, wid = t >> 6;
    const int G = lane >> 4, hl = lane & 15;

    // ---- XCD-affinity block remap (HW round-robins blockIdx % 8 across XCDs).
    // All 64 w-columns of one (b,d) group land on ONE XCD so its 4MB L2 holds the
    // group's rep slice exactly once; partial out-lines merge in that L2 too.
    const int j = blockIdx.x;
    const int x = j & 7;                         // XCD
    const int p = j >> 3;                        // position within XCD (0..191)
    const int group = ((p >> 6) << 3) + x;       // (b*ND+d) in [0,24), group%8 == x
    const int w = p & 63;
    const int d = group % ND;
    const int b = group / ND;
    const long base_bd = (long)b*(NC*CSTRIDE) + (long)d*(NH*NW) + w;

    // ================= stage X -> LDS bf16 (swizzled), thread t owns row h=t ==========
    {
        const int h = t;
        const long rbase = base_bd + (long)h*NW;
#pragma unroll
        for (int c8 = 0; c8 < 8; ++c8){
            U4S8 u;
            ushort_t* s = (ushort_t*)&u;
#pragma unroll
            for (int jj = 0; jj < 8; ++jj)
                s[jj] = bf_round(rep[rbase + (long)(c8*8 + jj)*CSTRIDE]);
            *(uint4*)(BUFB + row64_chunk(h, c8)) = u.u;
        }
    }
    // wave-local: each wave reads only its own 64 rows below (no barrier needed)

    // X A-frags, shared by all three projections: row h = 64*wid+16*ht+hl, k c = 32m+8G+j
    U4S8 xafr[4][2];
#pragma unroll
    for (int ht = 0; ht < 4; ++ht)
#pragma unroll
        for (int m = 0; m < 2; ++m)
            xafr[ht][m].u = *(const uint4*)(BUFB + row64_chunk(64*wid + 16*ht + hl, 4*m + G));

    // weight B/A-frag builder: lane needs W[hl+16*ot][32m+8G .. +8] as bf16x8
    auto wfrag = [&](const float* W, int ot, int m)->U4S8 {
        const float* p2 = W + (hl + 16*ot)*NC + 32*m + 8*G;
        float4 f0 = *(const float4*)p2;
        float4 f1 = *(const float4*)(p2 + 4);
        U4S8 u; ushort_t* s = (ushort_t*)&u;
        s[0]=bf_round(f0.x); s[1]=bf_round(f0.y); s[2]=bf_round(f0.z); s[3]=bf_round(f0.w);
        s[4]=bf_round(f1.x); s[5]=bf_round(f1.y); s[6]=bf_round(f1.z); s[7]=bf_round(f1.w);
        return u;
    };

    // projection: D[h,o] = relu(X·W^T + b) * scale ; D rows h (tile ht), cols o (tile ot)
    auto do_proj = [&](const float* W, const float* bias, float scale, f32x4 (&acc)[4][4]){
        U4S8 bw[4][2];
#pragma unroll
        for (int ot = 0; ot < 4; ++ot){ bw[ot][0] = wfrag(W, ot, 0); bw[ot][1] = wfrag(W, ot, 1); }
        float bb[4];
#pragma unroll
        for (int ot = 0; ot < 4; ++ot) bb[ot] = bias[hl + 16*ot];
#pragma unroll
        for (int ht = 0; ht < 4; ++ht)
#pragma unroll
            for (int ot = 0; ot < 4; ++ot){
                f32x4 a = {0.f, 0.f, 0.f, 0.f};
                a = __builtin_amdgcn_mfma_f32_16x16x32_bf16(xafr[ht][0].s, bw[ot][0].s, a, 0, 0, 0);
                a = __builtin_amdgcn_mfma_f32_16x16x32_bf16(xafr[ht][1].s, bw[ot][1].s, a, 0, 0, 0);
#pragma unroll
                for (int r = 0; r < 4; ++r) a[r] = fmaxf(a[r] + bb[ot], 0.f) * scale;
                acc[ht][ot] = a;
            }
    };

    // ---- Q projection -> bounce through BUFA (own quarter) -> B-frags in regs ----
    {
        f32x4 qa[4][4];
        do_proj(Wq, bq, 0.125f, qa);   // fold 1/sqrt(C)
#pragma unroll
        for (int ht = 0; ht < 4; ++ht)
#pragma unroll
            for (int ot = 0; ot < 4; ++ot)
#pragma unroll
                for (int r = 0; r < 4; ++r){
                    int h = 64*wid + 16*ht + 4*G + r;
                    int o = hl + 16*ot;
                    *(ushort_t*)(BUFA + row64_off(h, o)) = bf_round(qa[ht][ot][r]);
                }
    }
    U4S8 qfr[4][2];
#pragma unroll
    for (int ht = 0; ht < 4; ++ht)
#pragma unroll
        for (int m = 0; m < 2; ++m)
            qfr[ht][m].u = *(const uint4*)(BUFA + row64_chunk(64*wid + 16*ht + hl, 4*m + G));

    // ---- K projection -> write K_lds (BUFA, own quarter; Q-bounce already consumed) ----
    {
        f32x4 ka[4][4];
        do_proj(Wk, bk, 1.0f, ka);
#pragma unroll
        for (int gt = 0; gt < 4; ++gt)
#pragma unroll
            for (int ot = 0; ot < 4; ++ot)
#pragma unroll
                for (int r = 0; r < 4; ++r){
                    int g = 64*wid + 16*gt + 4*G + r;
                    int o = hl + 16*ot;
                    *(ushort_t*)(BUFA + row64_off(g, o)) = bf_round(ka[gt][ot][r]);
                }
    }

    // ---- V projection (keep in regs until X fully dead across ALL waves) ----
    f32x4 va[4][4];
    do_proj(Wv, bv, 1.0f, va);

    __syncthreads();   // all waves done reading X (BUFB) -> safe to overwrite with Vt

#pragma unroll
    for (int gt = 0; gt < 4; ++gt)
#pragma unroll
        for (int ot = 0; ot < 4; ++ot)
#pragma unroll
            for (int r = 0; r < 4; ++r){
                int g = 64*wid + 16*gt + 4*G + r;
                int c = hl + 16*ot;
                *(ushort_t*)(BUFB + vt_off(c, g)) = bf_round(va[gt][ot][r]);
            }

    __syncthreads();   // K_lds + Vt_lds complete

    // ================= flash attention over g-tiles of 64 =================
    f32x4 oacc[4][4];   // [ct][ht]: O'[c,h]
#pragma unroll
    for (int ct = 0; ct < 4; ++ct)
#pragma unroll
        for (int ht = 0; ht < 4; ++ht) oacc[ct][ht] = (f32x4){0.f,0.f,0.f,0.f};
    float m_run[4], l_run[4];
#pragma unroll
    for (int ht = 0; ht < 4; ++ht){ m_run[ht] = -1e30f; l_run[ht] = 0.f; }

    const int srcq0 = (16*((2*G    ) & 3) + hl)*4;   // bpermute byte addrs
    const int srcq1 = (16*((2*G + 1) & 3) + hl)*4;

    for (int gb = 0; gb < NH; gb += 64){
        // S'[g,h] = K·Q^T : A = K rows g, B = Q^T cols h, k = o
        U4S8 kfr[4][2];
#pragma unroll
        for (int gt = 0; gt < 4; ++gt)
#pragma unroll
            for (int m = 0; m < 2; ++m)
                kfr[gt][m].u = *(const uint4*)(BUFA + row64_chunk(gb + 16*gt + hl, 4*m + G));

        f32x4 sacc[4][4];   // [gt][ht]
#pragma unroll
        for (int gt = 0; gt < 4; ++gt)
#pragma unroll
            for (int ht = 0; ht < 4; ++ht){
                f32x4 a = {0.f,0.f,0.f,0.f};
                a = __builtin_amdgcn_mfma_f32_16x16x32_bf16(kfr[gt][0].s, qfr[ht][0].s, a, 0,0,0);
                a = __builtin_amdgcn_mfma_f32_16x16x32_bf16(kfr[gt][1].s, qfr[ht][1].s, a, 0,0,0);
                sacc[gt][ht] = a;
            }

        // online softmax per h-col (lane holds 16 g-values per ht; 4 G-groups complete it)
        unsigned int pk[4][4][2];   // [ht][gt][pair] packed bf16 P
#pragma unroll
        for (int ht = 0; ht < 4; ++ht){
            float cm = -1e30f;
#pragma unroll
            for (int gt = 0; gt < 4; ++gt)
#pragma unroll
                for (int r = 0; r < 4; ++r) cm = fmaxf(cm, sacc[gt][ht][r]);
            cm = fmaxf(cm, __shfl_xor(cm, 16));
            cm = fmaxf(cm, __shfl_xor(cm, 32));
            const float mn  = fmaxf(m_run[ht], cm);
            const float corr = __expf(m_run[ht] - mn);
            m_run[ht] = mn;
            float ls = 0.f;
#pragma unroll
            for (int gt = 0; gt < 4; ++gt){
                f32x4 s = sacc[gt][ht];
                float e0 = __expf(s[0]-mn), e1 = __expf(s[1]-mn);
                float e2 = __expf(s[2]-mn), e3 = __expf(s[3]-mn);
                ls += (e0+e1)+(e2+e3);
                pk[ht][gt][0] = (unsigned int)bf_round(e0) | ((unsigned int)bf_round(e1) << 16);
                pk[ht][gt][1] = (unsigned int)bf_round(e2) | ((unsigned int)bf_round(e3) << 16);
            }
            ls += __shfl_xor(ls, 16);
            ls += __shfl_xor(ls, 32);
            l_run[ht] = l_run[ht]*corr + ls;
#pragma unroll
            for (int ct = 0; ct < 4; ++ct)
#pragma unroll
                for (int r = 0; r < 4; ++r) oacc[ct][ht][r] *= corr;
        }

        // V^T A-frags and P B-frags (in-register transpose via ds_bpermute), then PV
        U4S8 vfr[4][2];
#pragma unroll
        for (int ct = 0; ct < 4; ++ct)
#pragma unroll
            for (int m = 0; m < 2; ++m)
                vfr[ct][m].u = *(const uint4*)(BUFB + vt_chunk(16*ct + hl, (gb>>3) + 4*m + G));

#pragma unroll
        for (int m = 0; m < 2; ++m){
            U4S8 bfr[4];
#pragma unroll
            for (int ht = 0; ht < 4; ++ht){
                unsigned int wv[4];
#pragma unroll
                for (int jj = 0; jj < 4; ++jj){
                    const int src = (jj >> 1) ? srcq1 : srcq0;
                    const int p2  = jj & 1;
                    int rA = __builtin_amdgcn_ds_bpermute(src, (int)pk[ht][2*m  ][p2]);
                    int rB = __builtin_amdgcn_ds_bpermute(src, (int)pk[ht][2*m+1][p2]);
                    wv[jj] = (lane < 32) ? (unsigned int)rA : (unsigned int)rB;
                }
                bfr[ht].u = make_uint4(wv[0], wv[1], wv[2], wv[3]);
            }
#pragma unroll
            for (int ct = 0; ct < 4; ++ct)
#pragma unroll
                for (int ht = 0; ht < 4; ++ht)
                    oacc[ct][ht] = __builtin_amdgcn_mfma_f32_16x16x32_bf16(vfr[ct][m].s, bfr[ht].s, oacc[ct][ht], 0,0,0);
        }
    }

    // ================= epilogue: 1/l, O -> LDS (hi+lo bf16 split), FC, store ============
    float invl[4];
#pragma unroll
    for (int ht = 0; ht < 4; ++ht) invl[ht] = 1.f / l_run[ht];

    __syncthreads();   // all waves done reading K_lds / Vt_lds

#pragma unroll
    for (int ct = 0; ct < 4; ++ct)
#pragma unroll
        for (int ht = 0; ht < 4; ++ht)
#pragma unroll
            for (int r = 0; r < 4; ++r){
                float v = oacc[ct][ht][r] * invl[ht];
                ushort_t hi = bf_round(v);
                ushort_t lo = bf_round(v - bf_to_f(hi));
                int hrow = 64*wid + 16*ht + hl;
                int c = 16*ct + 4*G + r;
                *(ushort_t*)(BUFA + row64_off(hrow, c)) = hi;
                *(ushort_t*)(BUFB + row64_off(hrow, c)) = lo;
            }
    // wave-local below (own h-strip): no barrier needed

    U4S8 bh[4][2], bl[4][2];
#pragma unroll
    for (int ht = 0; ht < 4; ++ht)
#pragma unroll
        for (int m = 0; m < 2; ++m){
            bh[ht][m].u = *(const uint4*)(BUFA + row64_chunk(64*wid + 16*ht + hl, 4*m + G));
            bl[ht][m].u = *(const uint4*)(BUFB + row64_chunk(64*wid + 16*ht + hl, 4*m + G));
        }

    f32x4 yacc[4][4];
#pragma unroll
    for (int ot = 0; ot < 4; ++ot)
#pragma unroll
        for (int ht = 0; ht < 4; ++ht) yacc[ot][ht] = (f32x4){0.f,0.f,0.f,0.f};

#pragma unroll
    for (int ot = 0; ot < 4; ++ot)
#pragma unroll
        for (int m = 0; m < 2; ++m){
            U4S8 wf = wfrag(Wf, ot, m);
#pragma unroll
            for (int ht = 0; ht < 4; ++ht){
                yacc[ot][ht] = __builtin_amdgcn_mfma_f32_16x16x32_bf16(wf.s, bh[ht][m].s, yacc[ot][ht], 0,0,0);
                yacc[ot][ht] = __builtin_amdgcn_mfma_f32_16x16x32_bf16(wf.s, bl[ht][m].s, yacc[ot][ht], 0,0,0);
            }
        }

    float bfv[4][4];
#pragma unroll
    for (int ot = 0; ot < 4; ++ot)
#pragma unroll
        for (int r = 0; r < 4; ++r) bfv[ot][r] = bfc[16*ot + 4*G + r];

#pragma unroll
    for (int ot = 0; ot < 4; ++ot)
#pragma unroll
        for (int ht = 0; ht < 4; ++ht)
#pragma unroll
            for (int r = 0; r < 4; ++r){
                int o = 16*ot + 4*G + r;
                int h = 64*wid + 16*ht + hl;
                float y = fmaxf(yacc[ot][ht][r] + bfv[ot][r], 0.f);
                out[base_bd + (long)o*CSTRIDE + (long)h*NW] = y;
            }
}

extern "C" void kernel_launch(void* const* d_in, const int* in_sizes, int n_in,
                              void* d_out, int out_size, void* d_ws, size_t ws_size,
                              hipStream_t stream) {
    (void)in_sizes; (void)n_in; (void)d_ws; (void)ws_size; (void)out_size;
    const float* rep = (const float*)d_in[0];
    const float* Wq  = (const float*)d_in[1];
    const float* bq  = (const float*)d_in[2];
    const float* Wk  = (const float*)d_in[3];
    const float* bk  = (const float*)d_in[4];
    const float* Wv  = (const float*)d_in[5];
    const float* bv  = (const float*)d_in[6];
    const float* Wf  = (const float*)d_in[7];
    const float* bfc = (const float*)d_in[8];
    float* out = (float*)d_out;

    dim3 grid(NB*ND*NW);   // 1536 blocks: one per (b,d,w), XCD-affinity remapped in-kernel
    dim3 block(256);       // 4 waves; wave wid owns h-strip [64*wid, 64*wid+64)
    sa_mfma<<<grid, block, 0, stream>>>(rep, Wq, bq, Wk, bk, Wv, bv, Wf, bfc, out);
}

// Round 4
// 172.415 us; speedup vs baseline: 32.0203x; 1.4122x over previous
//
#include <hip/hip_runtime.h>

typedef float f32x4 __attribute__((ext_vector_type(4)));
typedef short bf16x8 __attribute__((ext_vector_type(8)));
typedef unsigned short ushort_t;

#define NB 2
#define NC 64
#define ND 12
#define NH 256
#define NW 64
#define CSTRIDE (ND*NH*NW)   // 196608
#define QSZ_ELEMS (24*64*256*64)          // 25,165,824 bf16 elems per tensor
#define WS_NEED   ((size_t)3*QSZ_ELEMS*2) // 150,994,944 bytes

__device__ __forceinline__ ushort_t bf_round(float f){
    unsigned int u = __float_as_uint(f);
    return (ushort_t)((u + 0x7fffu + ((u >> 16) & 1u)) >> 16);   // RNE
}
__device__ __forceinline__ float bf_to_f(ushort_t s){ return __uint_as_float(((unsigned int)s) << 16); }

union U4S8 { uint4 u; bf16x8 s; };

// swizzled byte offsets: [R][64]-bf16 row-major, 8-elem (16B) chunks, chunk ^= row&7
__device__ __forceinline__ int row64_off(int r, int o){
    return r*128 + ((((o>>3) ^ (r&7)))<<4) + (o&7)*2;
}
__device__ __forceinline__ int row64_chunk(int r, int kchunk){
    return r*128 + (((kchunk ^ (r&7)))<<4);
}
// Vt: [64 c][256 g] bf16, rowbytes 512, 32 chunks, chunk ^= c&7
__device__ __forceinline__ int vt_off(int c, int g){
    return c*512 + ((((g>>3) ^ (c&7)))<<4) + (g&7)*2;
}
__device__ __forceinline__ int vt_chunk(int c, int gchunk){
    return c*512 + (((gchunk ^ (c&7)))<<4);
}

// weight frag: lane (hl,G) holds W[hl+16*ot][32m+8G .. +8] as bf16x8
__device__ __forceinline__ U4S8 wfrag_f(const float* W, int hl, int G, int ot, int m){
    const float* p2 = W + (hl + 16*ot)*NC + 32*m + 8*G;
    float4 f0 = *(const float4*)p2;
    float4 f1 = *(const float4*)(p2 + 4);
    U4S8 u; ushort_t* s = (ushort_t*)&u;
    s[0]=bf_round(f0.x); s[1]=bf_round(f0.y); s[2]=bf_round(f0.z); s[3]=bf_round(f0.w);
    s[4]=bf_round(f1.x); s[5]=bf_round(f1.y); s[6]=bf_round(f1.z); s[7]=bf_round(f1.w);
    return u;
}

// ===================== Kernel 1: QKV projection, coalesced =====================
// block = (bd, h-tile of 4) covering all 64 w. Local row n = hh*64 + w (hh=n>>6).
__global__ __launch_bounds__(256, 2) void k1_proj(
    const float* __restrict__ rep,
    const float* __restrict__ Wq, const float* __restrict__ bq,
    const float* __restrict__ Wk, const float* __restrict__ bk,
    const float* __restrict__ Wv, const float* __restrict__ bv,
    ushort_t* __restrict__ qws, ushort_t* __restrict__ kws, ushort_t* __restrict__ vws)
{
    __shared__ __align__(16) unsigned char smem[65536];
    unsigned char* XL = smem;          // X [256 n][64 c] row64, 32 KB
    unsigned char* OB = smem + 32768;  // bounce [256 n][64 o] row64, 32 KB

    const int t = threadIdx.x, lane = t & 63, wid = t >> 6;
    const int G = lane >> 4, hl = lane & 15;
    const int blk = blockIdx.x;
    const int bd = blk >> 6;
    const int h0 = (blk & 63) * 4;
    const int d = bd % ND, b = bd / ND;
    const long dbase2 = (long)b*NC*CSTRIDE + (long)d*(NH*NW) + (long)h0*NW; // + c*CSTRIDE + n

    // ---- stage X tile: fully coalesced (per instr: 64 consecutive floats per c) ----
#pragma unroll
    for (int oct = 0; oct < 8; ++oct){
        float f[8];
#pragma unroll
        for (int j = 0; j < 8; ++j)
            f[j] = rep[dbase2 + (long)(8*oct + j)*CSTRIDE + t];
        U4S8 u; ushort_t* s = (ushort_t*)&u;
#pragma unroll
        for (int j = 0; j < 8; ++j) s[j] = bf_round(f[j]);
        *(uint4*)(XL + row64_chunk(t, oct)) = u.u;
    }
    __syncthreads();

    U4S8 xa[4][2];
#pragma unroll
    for (int nt = 0; nt < 4; ++nt)
#pragma unroll
        for (int m = 0; m < 2; ++m)
            xa[nt][m].u = *(const uint4*)(XL + row64_chunk(64*wid + 16*nt + hl, 4*m + G));

    auto pass = [&](const float* W, const float* bias, float scale, ushort_t* dst){
        U4S8 bw[4][2];
        float bb[4];
#pragma unroll
        for (int ot = 0; ot < 4; ++ot){
            bw[ot][0] = wfrag_f(W, hl, G, ot, 0);
            bw[ot][1] = wfrag_f(W, hl, G, ot, 1);
            bb[ot] = bias[hl + 16*ot];
        }
        f32x4 acc[4][4];
#pragma unroll
        for (int nt = 0; nt < 4; ++nt)
#pragma unroll
            for (int ot = 0; ot < 4; ++ot){
                f32x4 a = {0.f,0.f,0.f,0.f};
                a = __builtin_amdgcn_mfma_f32_16x16x32_bf16(xa[nt][0].s, bw[ot][0].s, a, 0,0,0);
                a = __builtin_amdgcn_mfma_f32_16x16x32_bf16(xa[nt][1].s, bw[ot][1].s, a, 0,0,0);
#pragma unroll
                for (int r = 0; r < 4; ++r) a[r] = fmaxf(a[r] + bb[ot], 0.f) * scale;
                acc[nt][ot] = a;
            }
        // scatter D[n,o] -> bounce LDS (rows wave-owned)
#pragma unroll
        for (int nt = 0; nt < 4; ++nt)
#pragma unroll
            for (int ot = 0; ot < 4; ++ot)
#pragma unroll
                for (int r = 0; r < 4; ++r){
                    int n = 64*wid + 16*nt + 4*G + r;
                    int o = hl + 16*ot;
                    *(ushort_t*)(OB + row64_off(n, o)) = bf_round(acc[nt][ot][r]);
                }
        __syncthreads();
        // full-line ws writes: chunk (n, c8); ws row = (bd*64 + w)*256 + h0 + hh
#pragma unroll
        for (int i = 0; i < 8; ++i){
            int g2 = i*256 + t; int n = g2 >> 3; int c8 = g2 & 7;
            uint4 u = *(const uint4*)(OB + row64_chunk(n, c8));
            long row_g = ((long)bd*64 + (n & 63))*256 + h0 + (n >> 6);
            *(uint4*)((unsigned char*)dst + row_g*128 + c8*16) = u;
        }
        __syncthreads();
    };
    pass(Wq, bq, 0.125f, qws);   // fold 1/sqrt(C)
    pass(Wk, bk, 1.0f,   kws);
    pass(Wv, bv, 1.0f,   vws);
}

// ===================== Kernel 2: attention per (bd,w), coalesced ws I/O =====================
__global__ __launch_bounds__(256, 2) void k2_attn(
    ushort_t* __restrict__ qws, const ushort_t* __restrict__ kws, const ushort_t* __restrict__ vws)
{
    __shared__ __align__(16) unsigned char smem[65536];
    unsigned char* KL = smem;          // K [256 g][64 c] row64 -> later O-bounce [h][c]
    unsigned char* VT = smem + 32768;  // Vt [64 c][256 g]

    const int t = threadIdx.x, lane = t & 63, wid = t >> 6;
    const int G = lane >> 4, hl = lane & 15;
    const int bdw = blockIdx.x;
    ushort_t* qslice = qws + (size_t)bdw*16384;          // [h][c], also O dst
    const unsigned char* kslice = (const unsigned char*)(kws + (size_t)bdw*16384);
    const unsigned char* vslice = (const unsigned char*)(vws + (size_t)bdw*16384);

    // ---- stage K (b128 direct) and V (transpose scatter) ----
#pragma unroll
    for (int i = 0; i < 8; ++i){
        int g2 = i*256 + t; int g = g2 >> 3; int c8 = g2 & 7;
        uint4 ku = *(const uint4*)(kslice + g2*16);
        *(uint4*)(KL + row64_chunk(g, c8)) = ku;
        U4S8 vu; vu.u = *(const uint4*)(vslice + g2*16);
#pragma unroll
        for (int j = 0; j < 8; ++j)
            *(ushort_t*)(VT + vt_off(8*c8 + j, g)) = (ushort_t)vu.s[j];
    }
    __syncthreads();

    // Q B-frags direct from global (plain [h][c] rows, octet 4m+G at byte (4m+G)*16)
    U4S8 qfr[4][2];
#pragma unroll
    for (int ht = 0; ht < 4; ++ht)
#pragma unroll
        for (int m = 0; m < 2; ++m)
            qfr[ht][m].u = *(const uint4*)((const unsigned char*)qslice
                              + (64*wid + 16*ht + hl)*128 + (4*m + G)*16);

    // ================= flash attention over g-tiles of 64 (round-3 core) ================
    f32x4 oacc[4][4];
#pragma unroll
    for (int ct = 0; ct < 4; ++ct)
#pragma unroll
        for (int ht = 0; ht < 4; ++ht) oacc[ct][ht] = (f32x4){0.f,0.f,0.f,0.f};
    float m_run[4], l_run[4];
#pragma unroll
    for (int ht = 0; ht < 4; ++ht){ m_run[ht] = -1e30f; l_run[ht] = 0.f; }

    const int srcq0 = (16*((2*G    ) & 3) + hl)*4;
    const int srcq1 = (16*((2*G + 1) & 3) + hl)*4;

    for (int gb = 0; gb < NH; gb += 64){
        U4S8 kfr[4][2];
#pragma unroll
        for (int gt = 0; gt < 4; ++gt)
#pragma unroll
            for (int m = 0; m < 2; ++m)
                kfr[gt][m].u = *(const uint4*)(KL + row64_chunk(gb + 16*gt + hl, 4*m + G));

        f32x4 sacc[4][4];
#pragma unroll
        for (int gt = 0; gt < 4; ++gt)
#pragma unroll
            for (int ht = 0; ht < 4; ++ht){
                f32x4 a = {0.f,0.f,0.f,0.f};
                a = __builtin_amdgcn_mfma_f32_16x16x32_bf16(kfr[gt][0].s, qfr[ht][0].s, a, 0,0,0);
                a = __builtin_amdgcn_mfma_f32_16x16x32_bf16(kfr[gt][1].s, qfr[ht][1].s, a, 0,0,0);
                sacc[gt][ht] = a;
            }

        unsigned int pk[4][4][2];
#pragma unroll
        for (int ht = 0; ht < 4; ++ht){
            float cm = -1e30f;
#pragma unroll
            for (int gt = 0; gt < 4; ++gt)
#pragma unroll
                for (int r = 0; r < 4; ++r) cm = fmaxf(cm, sacc[gt][ht][r]);
            cm = fmaxf(cm, __shfl_xor(cm, 16));
            cm = fmaxf(cm, __shfl_xor(cm, 32));
            const float mn  = fmaxf(m_run[ht], cm);
            const float corr = __expf(m_run[ht] - mn);
            m_run[ht] = mn;
            float ls = 0.f;
#pragma unroll
            for (int gt = 0; gt < 4; ++gt){
                f32x4 s = sacc[gt][ht];
                float e0 = __expf(s[0]-mn), e1 = __expf(s[1]-mn);
                float e2 = __expf(s[2]-mn), e3 = __expf(s[3]-mn);
                ls += (e0+e1)+(e2+e3);
                pk[ht][gt][0] = (unsigned int)bf_round(e0) | ((unsigned int)bf_round(e1) << 16);
                pk[ht][gt][1] = (unsigned int)bf_round(e2) | ((unsigned int)bf_round(e3) << 16);
            }
            ls += __shfl_xor(ls, 16);
            ls += __shfl_xor(ls, 32);
            l_run[ht] = l_run[ht]*corr + ls;
#pragma unroll
            for (int ct = 0; ct < 4; ++ct)
#pragma unroll
                for (int r = 0; r < 4; ++r) oacc[ct][ht][r] *= corr;
        }

        U4S8 vfr[4][2];
#pragma unroll
        for (int ct = 0; ct < 4; ++ct)
#pragma unroll
            for (int m = 0; m < 2; ++m)
                vfr[ct][m].u = *(const uint4*)(VT + vt_chunk(16*ct + hl, (gb>>3) + 4*m + G));

#pragma unroll
        for (int m = 0; m < 2; ++m){
            U4S8 bfr[4];
#pragma unroll
            for (int ht = 0; ht < 4; ++ht){
                unsigned int wv[4];
#pragma unroll
                for (int jj = 0; jj < 4; ++jj){
                    const int src = (jj >> 1) ? srcq1 : srcq0;
                    const int p2  = jj & 1;
                    int rA = __builtin_amdgcn_ds_bpermute(src, (int)pk[ht][2*m  ][p2]);
                    int rB = __builtin_amdgcn_ds_bpermute(src, (int)pk[ht][2*m+1][p2]);
                    wv[jj] = (lane < 32) ? (unsigned int)rA : (unsigned int)rB;
                }
                bfr[ht].u = make_uint4(wv[0], wv[1], wv[2], wv[3]);
            }
#pragma unroll
            for (int ct = 0; ct < 4; ++ct)
#pragma unroll
                for (int ht = 0; ht < 4; ++ht)
                    oacc[ct][ht] = __builtin_amdgcn_mfma_f32_16x16x32_bf16(vfr[ct][m].s, bfr[ht].s, oacc[ct][ht], 0,0,0);
        }
    }

    // ---- epilogue: normalize, bounce O[h][c] through KL, coalesced write to qslice ----
    float invl[4];
#pragma unroll
    for (int ht = 0; ht < 4; ++ht) invl[ht] = 1.f / l_run[ht];

    __syncthreads();   // all waves done with KL/VT
#pragma unroll
    for (int ct = 0; ct < 4; ++ct)
#pragma unroll
        for (int ht = 0; ht < 4; ++ht)
#pragma unroll
            for (int r = 0; r < 4; ++r){
                int h = 64*wid + 16*ht + hl;
                int c = 16*ct + 4*G + r;
                *(ushort_t*)(KL + row64_off(h, c)) = bf_round(oacc[ct][ht][r] * invl[ht]);
            }
    __syncthreads();
#pragma unroll
    for (int i = 0; i < 8; ++i){
        int g2 = i*256 + t;
        uint4 u = *(const uint4*)(KL + row64_chunk(g2 >> 3, g2 & 7));
        *(uint4*)((unsigned char*)qslice + g2*16) = u;
    }
}

// ===================== Kernel 3: FC + ReLU + transpose-out, coalesced =====================
__global__ __launch_bounds__(256, 2) void k3_fc(
    const ushort_t* __restrict__ ows, const float* __restrict__ Wf, const float* __restrict__ bfc,
    float* __restrict__ out)
{
    __shared__ __align__(16) float YL[16384];   // [256 n][64 o], o swizzled, 64 KB

    const int t = threadIdx.x, lane = t & 63, wid = t >> 6;
    const int G = lane >> 4, hl = lane & 15;
    const int blk = blockIdx.x;
    const int bd = blk >> 6;
    const int h0 = (blk & 63) * 4;
    const int d = bd % ND, b = bd / ND;

    // A-frags: O rows (w = 16nt+hl, h = h0+wid), octet 4m+G
    U4S8 xa[4][2];
#pragma unroll
    for (int nt = 0; nt < 4; ++nt)
#pragma unroll
        for (int m = 0; m < 2; ++m){
            long row_g = ((long)bd*64 + (16*nt + hl))*256 + h0 + wid;
            xa[nt][m].u = *(const uint4*)((const unsigned char*)ows + row_g*128 + (4*m + G)*16);
        }

    U4S8 bw[4][2];
    float bb[4];
#pragma unroll
    for (int ot = 0; ot < 4; ++ot){
        bw[ot][0] = wfrag_f(Wf, hl, G, ot, 0);
        bw[ot][1] = wfrag_f(Wf, hl, G, ot, 1);
        bb[ot] = bfc[hl + 16*ot];
    }

    f32x4 acc[4][4];
#pragma unroll
    for (int nt = 0; nt < 4; ++nt)
#pragma unroll
        for (int ot = 0; ot < 4; ++ot){
            f32x4 a = {0.f,0.f,0.f,0.f};
            a = __builtin_amdgcn_mfma_f32_16x16x32_bf16(xa[nt][0].s, bw[ot][0].s, a, 0,0,0);
            a = __builtin_amdgcn_mfma_f32_16x16x32_bf16(xa[nt][1].s, bw[ot][1].s, a, 0,0,0);
#pragma unroll
            for (int r = 0; r < 4; ++r) a[r] = fmaxf(a[r] + bb[ot], 0.f);
            acc[nt][ot] = a;
        }

    // scatter Y[n][o] -> LDS (o ^= (n>>2)&31 swizzle)
#pragma unroll
    for (int nt = 0; nt < 4; ++nt)
#pragma unroll
        for (int ot = 0; ot < 4; ++ot)
#pragma unroll
            for (int r = 0; r < 4; ++r){
                int n = 64*wid + 16*nt + 4*G + r;
                int o = hl + 16*ot;
                YL[(n<<6) + (o ^ ((n>>2)&31))] = acc[nt][ot][r];
            }
    __syncthreads();

    // coalesced out writes: per instr one o, 1KB contiguous (4h x 64w)
    const long base3 = (long)b*NC*CSTRIDE + (long)d*(NH*NW) + (long)h0*NW;
#pragma unroll
    for (int i = 0; i < 16; ++i){
        int idx = i*1024 + t*4;
        int o = idx >> 8;
        int n0 = idx & 255;
        int osw = o ^ (t & 31);
        float4 v;
        v.x = YL[((n0+0)<<6) + osw];
        v.y = YL[((n0+1)<<6) + osw];
        v.z = YL[((n0+2)<<6) + osw];
        v.w = YL[((n0+3)<<6) + osw];
        *(float4*)(&out[base3 + (long)o*CSTRIDE + n0]) = v;
    }
}

// ===================== Fallback: round-3 fused kernel (proven) =====================
__global__ __launch_bounds__(256, 2) void sa_mfma(
    const float* __restrict__ rep,
    const float* __restrict__ Wq, const float* __restrict__ bq,
    const float* __restrict__ Wk, const float* __restrict__ bk,
    const float* __restrict__ Wv, const float* __restrict__ bv,
    const float* __restrict__ Wf, const float* __restrict__ bfc,
    float* __restrict__ out)
{
    __shared__ __align__(16) unsigned char smem[65536];
    unsigned char* BUFA = smem;
    unsigned char* BUFB = smem + 32768;

    const int t = threadIdx.x, lane = t & 63, wid = t >> 6;
    const int G = lane >> 4, hl = lane & 15;
    const int j = blockIdx.x;
    const int x = j & 7;
    const int p = j >> 3;
    const int group = ((p >> 6) << 3) + x;
    const int w = p & 63;
    const int d = group % ND;
    const int b = group / ND;
    const long base_bd = (long)b*(NC*CSTRIDE) + (long)d*(NH*NW) + w;

    {
        const int h = t;
        const long rbase = base_bd + (long)h*NW;
#pragma unroll
        for (int c8 = 0; c8 < 8; ++c8){
            U4S8 u;
            ushort_t* s = (ushort_t*)&u;
#pragma unroll
            for (int jj = 0; jj < 8; ++jj)
                s[jj] = bf_round(rep[rbase + (long)(c8*8 + jj)*CSTRIDE]);
            *(uint4*)(BUFB + row64_chunk(h, c8)) = u.u;
        }
    }
    U4S8 xafr[4][2];
#pragma unroll
    for (int ht = 0; ht < 4; ++ht)
#pragma unroll
        for (int m = 0; m < 2; ++m)
            xafr[ht][m].u = *(const uint4*)(BUFB + row64_chunk(64*wid + 16*ht + hl, 4*m + G));

    auto do_proj = [&](const float* W, const float* bias, float scale, f32x4 (&acc)[4][4]){
        U4S8 bw[4][2];
#pragma unroll
        for (int ot = 0; ot < 4; ++ot){ bw[ot][0] = wfrag_f(W, hl, G, ot, 0); bw[ot][1] = wfrag_f(W, hl, G, ot, 1); }
        float bb[4];
#pragma unroll
        for (int ot = 0; ot < 4; ++ot) bb[ot] = bias[hl + 16*ot];
#pragma unroll
        for (int ht = 0; ht < 4; ++ht)
#pragma unroll
            for (int ot = 0; ot < 4; ++ot){
                f32x4 a = {0.f, 0.f, 0.f, 0.f};
                a = __builtin_amdgcn_mfma_f32_16x16x32_bf16(xafr[ht][0].s, bw[ot][0].s, a, 0, 0, 0);
                a = __builtin_amdgcn_mfma_f32_16x16x32_bf16(xafr[ht][1].s, bw[ot][1].s, a, 0, 0, 0);
#pragma unroll
                for (int r = 0; r < 4; ++r) a[r] = fmaxf(a[r] + bb[ot], 0.f) * scale;
                acc[ht][ot] = a;
            }
    };

    {
        f32x4 qa[4][4];
        do_proj(Wq, bq, 0.125f, qa);
#pragma unroll
        for (int ht = 0; ht < 4; ++ht)
#pragma unroll
            for (int ot = 0; ot < 4; ++ot)
#pragma unroll
                for (int r = 0; r < 4; ++r){
                    int h = 64*wid + 16*ht + 4*G + r;
                    int o = hl + 16*ot;
                    *(ushort_t*)(BUFA + row64_off(h, o)) = bf_round(qa[ht][ot][r]);
                }
    }
    U4S8 qfr[4][2];
#pragma unroll
    for (int ht = 0; ht < 4; ++ht)
#pragma unroll
        for (int m = 0; m < 2; ++m)
            qfr[ht][m].u = *(const uint4*)(BUFA + row64_chunk(64*wid + 16*ht + hl, 4*m + G));

    {
        f32x4 ka[4][4];
        do_proj(Wk, bk, 1.0f, ka);
#pragma unroll
        for (int gt = 0; gt < 4; ++gt)
#pragma unroll
            for (int ot = 0; ot < 4; ++ot)
#pragma unroll
                for (int r = 0; r < 4; ++r){
                    int g = 64*wid + 16*gt + 4*G + r;
                    int o = hl + 16*ot;
                    *(ushort_t*)(BUFA + row64_off(g, o)) = bf_round(ka[gt][ot][r]);
                }
    }
    f32x4 va[4][4];
    do_proj(Wv, bv, 1.0f, va);
    __syncthreads();
#pragma unroll
    for (int gt = 0; gt < 4; ++gt)
#pragma unroll
        for (int ot = 0; ot < 4; ++ot)
#pragma unroll
            for (int r = 0; r < 4; ++r){
                int g = 64*wid + 16*gt + 4*G + r;
                int c = hl + 16*ot;
                *(ushort_t*)(BUFB + vt_off(c, g)) = bf_round(va[gt][ot][r]);
            }
    __syncthreads();

    f32x4 oacc[4][4];
#pragma unroll
    for (int ct = 0; ct < 4; ++ct)
#pragma unroll
        for (int ht = 0; ht < 4; ++ht) oacc[ct][ht] = (f32x4){0.f,0.f,0.f,0.f};
    float m_run[4], l_run[4];
#pragma unroll
    for (int ht = 0; ht < 4; ++ht){ m_run[ht] = -1e30f; l_run[ht] = 0.f; }

    const int srcq0 = (16*((2*G    ) & 3) + hl)*4;
    const int srcq1 = (16*((2*G + 1) & 3) + hl)*4;

    for (int gb = 0; gb < NH; gb += 64){
        U4S8 kfr[4][2];
#pragma unroll
        for (int gt = 0; gt < 4; ++gt)
#pragma unroll
            for (int m = 0; m < 2; ++m)
                kfr[gt][m].u = *(const uint4*)(BUFA + row64_chunk(gb + 16*gt + hl, 4*m + G));

        f32x4 sacc[4][4];
#pragma unroll
        for (int gt = 0; gt < 4; ++gt)
#pragma unroll
            for (int ht = 0; ht < 4; ++ht){
                f32x4 a = {0.f,0.f,0.f,0.f};
                a = __builtin_amdgcn_mfma_f32_16x16x32_bf16(kfr[gt][0].s, qfr[ht][0].s, a, 0,0,0);
                a = __builtin_amdgcn_mfma_f32_16x16x32_bf16(kfr[gt][1].s, qfr[ht][1].s, a, 0,0,0);
                sacc[gt][ht] = a;
            }

        unsigned int pk[4][4][2];
#pragma unroll
        for (int ht = 0; ht < 4; ++ht){
            float cm = -1e30f;
#pragma unroll
            for (int gt = 0; gt < 4; ++gt)
#pragma unroll
                for (int r = 0; r < 4; ++r) cm = fmaxf(cm, sacc[gt][ht][r]);
            cm = fmaxf(cm, __shfl_xor(cm, 16));
            cm = fmaxf(cm, __shfl_xor(cm, 32));
            const float mn  = fmaxf(m_run[ht], cm);
            const float corr = __expf(m_run[ht] - mn);
            m_run[ht] = mn;
            float ls = 0.f;
#pragma unroll
            for (int gt = 0; gt < 4; ++gt){
                f32x4 s = sacc[gt][ht];
                float e0 = __expf(s[0]-mn), e1 = __expf(s[1]-mn);
                float e2 = __expf(s[2]-mn), e3 = __expf(s[3]-mn);
                ls += (e0+e1)+(e2+e3);
                pk[ht][gt][0] = (unsigned int)bf_round(e0) | ((unsigned int)bf_round(e1) << 16);
                pk[ht][gt][1] = (unsigned int)bf_round(e2) | ((unsigned int)bf_round(e3) << 16);
            }
            ls += __shfl_xor(ls, 16);
            ls += __shfl_xor(ls, 32);
            l_run[ht] = l_run[ht]*corr + ls;
#pragma unroll
            for (int ct = 0; ct < 4; ++ct)
#pragma unroll
                for (int r = 0; r < 4; ++r) oacc[ct][ht][r] *= corr;
        }

        U4S8 vfr[4][2];
#pragma unroll
        for (int ct = 0; ct < 4; ++ct)
#pragma unroll
            for (int m = 0; m < 2; ++m)
                vfr[ct][m].u = *(const uint4*)(BUFB + vt_chunk(16*ct + hl, (gb>>3) + 4*m + G));

#pragma unroll
        for (int m = 0; m < 2; ++m){
            U4S8 bfr[4];
#pragma unroll
            for (int ht = 0; ht < 4; ++ht){
                unsigned int wv[4];
#pragma unroll
                for (int jj = 0; jj < 4; ++jj){
                    const int src = (jj >> 1) ? srcq1 : srcq0;
                    const int p2  = jj & 1;
                    int rA = __builtin_amdgcn_ds_bpermute(src, (int)pk[ht][2*m  ][p2]);
                    int rB = __builtin_amdgcn_ds_bpermute(src, (int)pk[ht][2*m+1][p2]);
                    wv[jj] = (lane < 32) ? (unsigned int)rA : (unsigned int)rB;
                }
                bfr[ht].u = make_uint4(wv[0], wv[1], wv[2], wv[3]);
            }
#pragma unroll
            for (int ct = 0; ct < 4; ++ct)
#pragma unroll
                for (int ht = 0; ht < 4; ++ht)
                    oacc[ct][ht] = __builtin_amdgcn_mfma_f32_16x16x32_bf16(vfr[ct][m].s, bfr[ht].s, oacc[ct][ht], 0,0,0);
        }
    }

    float invl[4];
#pragma unroll
    for (int ht = 0; ht < 4; ++ht) invl[ht] = 1.f / l_run[ht];
    __syncthreads();
#pragma unroll
    for (int ct = 0; ct < 4; ++ct)
#pragma unroll
        for (int ht = 0; ht < 4; ++ht)
#pragma unroll
            for (int r = 0; r < 4; ++r){
                float v = oacc[ct][ht][r] * invl[ht];
                ushort_t hi = bf_round(v);
                ushort_t lo = bf_round(v - bf_to_f(hi));
                int hrow = 64*wid + 16*ht + hl;
                int c = 16*ct + 4*G + r;
                *(ushort_t*)(BUFA + row64_off(hrow, c)) = hi;
                *(ushort_t*)(BUFB + row64_off(hrow, c)) = lo;
            }
    U4S8 bh[4][2], bl[4][2];
#pragma unroll
    for (int ht = 0; ht < 4; ++ht)
#pragma unroll
        for (int m = 0; m < 2; ++m){
            bh[ht][m].u = *(const uint4*)(BUFA + row64_chunk(64*wid + 16*ht + hl, 4*m + G));
            bl[ht][m].u = *(const uint4*)(BUFB + row64_chunk(64*wid + 16*ht + hl, 4*m + G));
        }

    f32x4 yacc[4][4];
#pragma unroll
    for (int ot = 0; ot < 4; ++ot)
#pragma unroll
        for (int ht = 0; ht < 4; ++ht) yacc[ot][ht] = (f32x4){0.f,0.f,0.f,0.f};
#pragma unroll
    for (int ot = 0; ot < 4; ++ot)
#pragma unroll
        for (int m = 0; m < 2; ++m){
            U4S8 wf = wfrag_f(Wf, hl, G, ot, m);
#pragma unroll
            for (int ht = 0; ht < 4; ++ht){
                yacc[ot][ht] = __builtin_amdgcn_mfma_f32_16x16x32_bf16(wf.s, bh[ht][m].s, yacc[ot][ht], 0,0,0);
                yacc[ot][ht] = __builtin_amdgcn_mfma_f32_16x16x32_bf16(wf.s, bl[ht][m].s, yacc[ot][ht], 0,0,0);
            }
        }
    float bfv[4][4];
#pragma unroll
    for (int ot = 0; ot < 4; ++ot)
#pragma unroll
        for (int r = 0; r < 4; ++r) bfv[ot][r] = bfc[16*ot + 4*G + r];
#pragma unroll
    for (int ot = 0; ot < 4; ++ot)
#pragma unroll
        for (int ht = 0; ht < 4; ++ht)
#pragma unroll
            for (int r = 0; r < 4; ++r){
                int o = 16*ot + 4*G + r;
                int h = 64*wid + 16*ht + hl;
                float y = fmaxf(yacc[ot][ht][r] + bfv[ot][r], 0.f);
                out[base_bd + (long)o*CSTRIDE + (long)h*NW] = y;
            }
}

extern "C" void kernel_launch(void* const* d_in, const int* in_sizes, int n_in,
                              void* d_out, int out_size, void* d_ws, size_t ws_size,
                              hipStream_t stream) {
    (void)in_sizes; (void)n_in; (void)out_size;
    const float* rep = (const float*)d_in[0];
    const float* Wq  = (const float*)d_in[1];
    const float* bq  = (const float*)d_in[2];
    const float* Wk  = (const float*)d_in[3];
    const float* bk  = (const float*)d_in[4];
    const float* Wv  = (const float*)d_in[5];
    const float* bv  = (const float*)d_in[6];
    const float* Wf  = (const float*)d_in[7];
    const float* bfc = (const float*)d_in[8];
    float* out = (float*)d_out;

    if (ws_size >= WS_NEED) {
        ushort_t* qws = (ushort_t*)d_ws;
        ushort_t* kws = qws + QSZ_ELEMS;
        ushort_t* vws = kws + QSZ_ELEMS;
        k1_proj<<<dim3(1536), dim3(256), 0, stream>>>(rep, Wq, bq, Wk, bk, Wv, bv, qws, kws, vws);
        k2_attn<<<dim3(1536), dim3(256), 0, stream>>>(qws, kws, vws);
        k3_fc  <<<dim3(1536), dim3(256), 0, stream>>>(qws, Wf, bfc, out);
    } else {
        sa_mfma<<<dim3(1536), dim3(256), 0, stream>>>(rep, Wq, bq, Wk, bk, Wv, bv, Wf, bfc, out);
    }
}